// Round 5
// baseline (421.814 us; speedup 1.0000x reference)
//
#include <hip/hip_runtime.h>
#include <hip/hip_bf16.h>
#include <math.h>

#define D 128
#define H 4
#define NEG_SLOPE 0.2f
#define LN_EPS 1e-5f
#define CE 64   // edges per softmax chunk in k_gat4

__device__ __forceinline__ float lrelu(float v) {
    return v > 0.f ? v : NEG_SLOPE * v;
}

// ---------- per-destination in-degree histogram (int atomics only) ----------
__global__ void k_count(const int* __restrict__ ei, int* __restrict__ cnt, int E) {
    int e = blockIdx.x * blockDim.x + threadIdx.x;
    if (e >= E) return;
    atomicAdd(&cnt[ei[E + e]], 1);
}

// ---------- hierarchical exclusive scan of cnt[N] -> off[N+1] ----------
__global__ void k_scan_part(const int* __restrict__ cnt, int* __restrict__ off,
                            int* __restrict__ bsum, int N) {
    __shared__ int sm[256];
    int i = blockIdx.x * 256 + threadIdx.x;
    int v = (i < N) ? cnt[i] : 0;
    sm[threadIdx.x] = v;
    __syncthreads();
    #pragma unroll
    for (int o = 1; o < 256; o <<= 1) {
        int t = (threadIdx.x >= (unsigned)o) ? sm[threadIdx.x - o] : 0;
        __syncthreads();
        sm[threadIdx.x] += t;
        __syncthreads();
    }
    if (i < N) off[i] = sm[threadIdx.x];
    if (threadIdx.x == 255) bsum[blockIdx.x] = sm[255];
}

__global__ void k_scan_top(int* __restrict__ bsum, int* __restrict__ off,
                           int NB, int N) {
    __shared__ int sm[256];
    int v = (threadIdx.x < (unsigned)NB) ? bsum[threadIdx.x] : 0;
    sm[threadIdx.x] = v;
    __syncthreads();
    #pragma unroll
    for (int o = 1; o < 256; o <<= 1) {
        int t = (threadIdx.x >= (unsigned)o) ? sm[threadIdx.x - o] : 0;
        __syncthreads();
        sm[threadIdx.x] += t;
        __syncthreads();
    }
    if (threadIdx.x < (unsigned)NB) bsum[threadIdx.x] = sm[threadIdx.x] - v;
    if (threadIdx.x == 255) off[N] = sm[255];
}

__global__ void k_scan_add(const int* __restrict__ cnt, int* __restrict__ off,
                           const int* __restrict__ bsum, int N) {
    int i = blockIdx.x * 256 + threadIdx.x;
    if (i < N) off[i] = off[i] - cnt[i] + bsum[blockIdx.x];
}

// ---------- CSR fill: adj2[slot] = {src, edge_id} (one 8B store) ----------
__global__ void k_fill(const int* __restrict__ ei, const int* __restrict__ off,
                       int* __restrict__ pos, int2* __restrict__ adj2, int E) {
    int e = blockIdx.x * blockDim.x + threadIdx.x;
    if (e >= E) return;
    int dst = ei[E + e];
    int slot = off[dst] + atomicAdd(&pos[dst], 1);
    adj2[slot] = make_int2(ei[e], e);
}

// ---------- GEMM: C[N,128] = A[N,128] @ W[128,128] ----------
// MODE 1: A explicit, bf16 out + fused attention dots.
// MODE 2: A synthesized from scatter-mean (x gathered via CSR, W_edge, b_edge),
//         f32 out + bias.
template <int MODE>
__global__ __launch_bounds__(256) void k_gemm(
        const float* __restrict__ A, const float* __restrict__ W,
        const float* __restrict__ bias, float* __restrict__ C,
        __hip_bfloat16* __restrict__ xhb, float* __restrict__ a_s,
        float* __restrict__ a_d, const float* __restrict__ att_s,
        const float* __restrict__ att_d,
        const float* __restrict__ x, const int2* __restrict__ adj2,
        const int* __restrict__ off,
        const float* __restrict__ W_edge, const float* __restrict__ b_edge,
        int N) {
    __shared__ float As[64][132];
    int tid = threadIdx.x;
    int n0 = blockIdx.x * 64;

    if (MODE == 2) {
        __shared__ float rowf[64][4];
        // gather-sum raw 3-dim edge features: 4 threads per row
        {
            int r = tid >> 2, t4 = tid & 3;
            int n = n0 + r;
            float s0 = 0.f, s1 = 0.f, s2 = 0.f;
            int degv = 0;
            if (n < N) {
                int beg = off[n], end = off[n + 1];
                degv = end - beg;
                for (int p = beg + t4; p < end; p += 4) {
                    const float* xr = x + (size_t)adj2[p].y * 3;
                    s0 += xr[0]; s1 += xr[1]; s2 += xr[2];
                }
            }
            s0 += __shfl_xor(s0, 1); s0 += __shfl_xor(s0, 2);
            s1 += __shfl_xor(s1, 1); s1 += __shfl_xor(s1, 2);
            s2 += __shfl_xor(s2, 1); s2 += __shfl_xor(s2, 2);
            if (t4 == 0)
                *reinterpret_cast<float4*>(rowf[r]) =
                    make_float4(s0, s1, s2, (float)degv);
        }
        __syncthreads();
        int d = tid & 127;
        float we0 = W_edge[d], we1 = W_edge[D + d], we2 = W_edge[2 * D + d];
        float be = b_edge[d];
        for (int r = tid >> 7; r < 64; r += 2) {
            float4 rv = *reinterpret_cast<float4*>(rowf[r]);
            float c = rv.w;
            As[r][d] = (rv.x * we0 + rv.y * we1 + rv.z * we2 + c * be)
                       / fmaxf(c, 1.f);
        }
    } else {
        for (int i = tid; i < 64 * 32; i += 256) {
            int r = i >> 5, q = i & 31;
            int n = n0 + r;
            float4 v = make_float4(0.f, 0.f, 0.f, 0.f);
            if (n < N) v = reinterpret_cast<const float4*>(A)[(size_t)n * 32 + q];
            *reinterpret_cast<float4*>(&As[r][q * 4]) = v;
        }
    }
    __syncthreads();

    int tx = tid & 15, ty = tid >> 4;
    int c0 = tx * 8, r0 = ty * 4;
    float acc[4][8];
    #pragma unroll
    for (int r = 0; r < 4; r++)
        #pragma unroll
        for (int c = 0; c < 8; c++) acc[r][c] = 0.f;

    const float4* Wv = reinterpret_cast<const float4*>(W);
    #pragma unroll 4
    for (int k = 0; k < D; k++) {
        float4 w0 = Wv[k * 32 + tx * 2];
        float4 w1 = Wv[k * 32 + tx * 2 + 1];
        #pragma unroll
        for (int r = 0; r < 4; r++) {
            float a = As[r0 + r][k];
            acc[r][0] += a * w0.x; acc[r][1] += a * w0.y;
            acc[r][2] += a * w0.z; acc[r][3] += a * w0.w;
            acc[r][4] += a * w1.x; acc[r][5] += a * w1.y;
            acc[r][6] += a * w1.z; acc[r][7] += a * w1.w;
        }
    }

    if (MODE == 2) {
        float b[8];
        #pragma unroll
        for (int c = 0; c < 8; c++) b[c] = bias[c0 + c];
        #pragma unroll
        for (int r = 0; r < 4; r++) {
            int n = n0 + r0 + r;
            if (n >= N) continue;
            float4 o0 = make_float4(acc[r][0] + b[0], acc[r][1] + b[1],
                                    acc[r][2] + b[2], acc[r][3] + b[3]);
            float4 o1 = make_float4(acc[r][4] + b[4], acc[r][5] + b[5],
                                    acc[r][6] + b[6], acc[r][7] + b[7]);
            reinterpret_cast<float4*>(C)[(size_t)n * 32 + tx * 2] = o0;
            reinterpret_cast<float4*>(C)[(size_t)n * 32 + tx * 2 + 1] = o1;
        }
    } else {
        float ats[8], atd[8];
        #pragma unroll
        for (int c = 0; c < 8; c++) { ats[c] = att_s[c0 + c]; atd[c] = att_d[c0 + c]; }
        #pragma unroll
        for (int r = 0; r < 4; r++) {
            int n = n0 + r0 + r;
            union { uint4 v; unsigned short s[8]; } pk;
            #pragma unroll
            for (int c = 0; c < 8; c++) {
                __hip_bfloat16 hb = __float2bfloat16(acc[r][c]);
                pk.s[c] = *reinterpret_cast<unsigned short*>(&hb);
            }
            float ps = 0.f, pd = 0.f;
            #pragma unroll
            for (int c = 0; c < 8; c++) { ps += acc[r][c] * ats[c]; pd += acc[r][c] * atd[c]; }
            ps += __shfl_xor(ps, 1); ps += __shfl_xor(ps, 2);
            pd += __shfl_xor(pd, 1); pd += __shfl_xor(pd, 2);
            if (n < N) {
                *reinterpret_cast<uint4*>(xhb + (size_t)n * D + c0) = pk.v;
                if ((tx & 3) == 0) {
                    a_s[n * H + (tx >> 2)] = ps;
                    a_d[n * H + (tx >> 2)] = pd;
                }
            }
        }
    }
}

// ---------- fused GAT aggregate + bias + LN (+ReLU) + residual ----------
// Persistent: fixed grid, each WAVE grid-strides over nodes independently.
// Lane layout: cl = lane&15 owns channels 8*cl..8*cl+7; sub = lane>>4 picks
// one of 4 edges per iteration (16B dwordx4 gather per lane).
__global__ __launch_bounds__(256) void k_gat4(
        const __hip_bfloat16* __restrict__ xhb, const int* __restrict__ off,
        const int2* __restrict__ adj2, const float* __restrict__ a_s,
        const float* __restrict__ a_d, const float* __restrict__ bias,
        const float* __restrict__ g, const float* __restrict__ bln,
        float* __restrict__ h, int N, int do_relu, int nwaves) {
    __shared__ float2 ws_all[4][CE * 4];   // {weight, src index (bits)}
    __shared__ int si_all[4][CE];
    int wid = threadIdx.x >> 6;
    int lane = threadIdx.x & 63;
    float2* ws = ws_all[wid];
    int* si = si_all[wid];

    int hA = lane & 3;              // phase-A head
    int cl = lane & 15;             // channel group: c0 = 8*cl
    int sub = lane >> 4;            // edge sub-slot
    int hb = cl >> 2;               // head of this lane's channels
    int c0 = cl * 8;

    for (int n = blockIdx.x * 4 + wid; n < N; n += nwaves) {
        int beg = off[n], end = off[n + 1];
        int deg = end - beg;
        int items = deg + 1;            // + self loop

        float adA = a_d[n * H + hA];
        float m = -INFINITY, den = 0.f;
        float acc[8];
        #pragma unroll
        for (int c = 0; c < 8; c++) acc[c] = 0.f;

        for (int base = 0; base < items; base += CE) {
            int ce = min(CE, items - base);
            int cep = (ce + 3) & ~3;

            // stage source indices (self-loop / pad -> n)
            if (lane < cep) {
                int p = base + lane;
                si[lane] = (p < deg) ? adj2[beg + p].x : n;
            }
            asm volatile("s_waitcnt lgkmcnt(0)" ::: "memory");

            // phase A: attention logits, online max
            float ev[4];
            int nj = 0;
            float lmax = -INFINITY;
            for (int t = lane; t < ce * 4; t += 64) {
                int s = si[t >> 2];
                float e = lrelu(a_s[s * H + hA] + adA);
                ev[nj++] = e;
                lmax = fmaxf(lmax, e);
            }
            #pragma unroll
            for (int o = 4; o < 64; o <<= 1) lmax = fmaxf(lmax, __shfl_xor(lmax, o));
            float newm = fmaxf(m, lmax);
            float rs = __expf(m - newm);          // 0 on first chunk

            float lsum = 0.f;
            {
                int j = 0;
                for (int t = lane; t < cep * 4; t += 64) {
                    float w = 0.f;
                    if (t < ce * 4) { w = __expf(ev[j++] - newm); lsum += w; }
                    ws[t] = make_float2(w, __int_as_float(si[t >> 2]));
                }
            }
            #pragma unroll
            for (int o = 4; o < 64; o <<= 1) lsum += __shfl_xor(lsum, o);
            den = den * rs + lsum;
            m = newm;

            float rsB = __shfl(rs, hb);
            #pragma unroll
            for (int c = 0; c < 8; c++) acc[c] *= rsB;

            asm volatile("s_waitcnt lgkmcnt(0)" ::: "memory");

            // phase B: weighted feature gather, 4 edges in flight per wave
            for (int p = 0; p < cep; p += 4) {
                int pp = p + sub;
                float2 wsv = ws[pp * 4 + hb];
                float w = wsv.x;
                int s = __float_as_int(wsv.y);
                uint4 u = *reinterpret_cast<const uint4*>(xhb + (size_t)s * D + c0);
                float f;
                f = __uint_as_float(u.x << 16);         acc[0] += w * f;
                f = __uint_as_float(u.x & 0xffff0000u); acc[1] += w * f;
                f = __uint_as_float(u.y << 16);         acc[2] += w * f;
                f = __uint_as_float(u.y & 0xffff0000u); acc[3] += w * f;
                f = __uint_as_float(u.z << 16);         acc[4] += w * f;
                f = __uint_as_float(u.z & 0xffff0000u); acc[5] += w * f;
                f = __uint_as_float(u.w << 16);         acc[6] += w * f;
                f = __uint_as_float(u.w & 0xffff0000u); acc[7] += w * f;
            }
            asm volatile("s_waitcnt lgkmcnt(0)" ::: "memory");
        }

        float denB = __shfl(den, hb);

        // combine the 4 edge sub-slots
        #pragma unroll
        for (int c = 0; c < 8; c++) {
            acc[c] += __shfl_xor(acc[c], 16);
            acc[c] += __shfl_xor(acc[c], 32);
        }

        float4 b0 = *reinterpret_cast<const float4*>(bias + c0);
        float4 b1 = *reinterpret_cast<const float4*>(bias + c0 + 4);
        float o[8];
        o[0] = acc[0] / denB + b0.x; o[1] = acc[1] / denB + b0.y;
        o[2] = acc[2] / denB + b0.z; o[3] = acc[3] / denB + b0.w;
        o[4] = acc[4] / denB + b1.x; o[5] = acc[5] / denB + b1.y;
        o[6] = acc[6] / denB + b1.z; o[7] = acc[7] / denB + b1.w;

        // LayerNorm (each channel appears 4x across the wave -> divide by 512)
        float s1 = 0.f;
        #pragma unroll
        for (int c = 0; c < 8; c++) s1 += o[c];
        #pragma unroll
        for (int os = 1; os < 64; os <<= 1) s1 += __shfl_xor(s1, os);
        float mu = s1 * (1.0f / 512.0f);
        float s2 = 0.f;
        #pragma unroll
        for (int c = 0; c < 8; c++) { float dv = o[c] - mu; s2 += dv * dv; }
        #pragma unroll
        for (int os = 1; os < 64; os <<= 1) s2 += __shfl_xor(s2, os);
        float inv = rsqrtf(s2 * (1.0f / 512.0f) + LN_EPS);

        if (sub == 0) {
            float4 g0 = *reinterpret_cast<const float4*>(g + c0);
            float4 g1 = *reinterpret_cast<const float4*>(g + c0 + 4);
            float4 l0 = *reinterpret_cast<const float4*>(bln + c0);
            float4 l1 = *reinterpret_cast<const float4*>(bln + c0 + 4);
            float y[8];
            y[0] = (o[0] - mu) * inv * g0.x + l0.x;
            y[1] = (o[1] - mu) * inv * g0.y + l0.y;
            y[2] = (o[2] - mu) * inv * g0.z + l0.z;
            y[3] = (o[3] - mu) * inv * g0.w + l0.w;
            y[4] = (o[4] - mu) * inv * g1.x + l1.x;
            y[5] = (o[5] - mu) * inv * g1.y + l1.y;
            y[6] = (o[6] - mu) * inv * g1.z + l1.z;
            y[7] = (o[7] - mu) * inv * g1.w + l1.w;
            if (do_relu) {
                #pragma unroll
                for (int c = 0; c < 8; c++) y[c] = fmaxf(y[c], 0.f);
            }
            float4 h0 = *reinterpret_cast<float4*>(h + (size_t)n * D + c0);
            float4 h1 = *reinterpret_cast<float4*>(h + (size_t)n * D + c0 + 4);
            h0.x += y[0]; h0.y += y[1]; h0.z += y[2]; h0.w += y[3];
            h1.x += y[4]; h1.y += y[5]; h1.z += y[6]; h1.w += y[7];
            *reinterpret_cast<float4*>(h + (size_t)n * D + c0) = h0;
            *reinterpret_cast<float4*>(h + (size_t)n * D + c0 + 4) = h1;
        }
    }
}

extern "C" void kernel_launch(void* const* d_in, const int* in_sizes, int n_in,
                              void* d_out, int out_size, void* d_ws, size_t ws_size,
                              hipStream_t stream) {
    const float* x       = (const float*)d_in[0];
    const int*   ei      = (const int*)  d_in[1];
    const float* W_edge  = (const float*)d_in[2];
    const float* b_edge  = (const float*)d_in[3];
    const float* W_node  = (const float*)d_in[4];
    const float* b_node  = (const float*)d_in[5];
    const float* lin_w   = (const float*)d_in[6];
    const float* att_src = (const float*)d_in[7];
    const float* att_dst = (const float*)d_in[8];
    const float* gat_b   = (const float*)d_in[9];
    const float* ln_g    = (const float*)d_in[10];
    const float* ln_b    = (const float*)d_in[11];

    int N = out_size / D;
    int E = in_sizes[1] / 2;
    int NB = (N + 255) / 256;

    char* w = (char*)d_ws;
    auto carve = [&](size_t bytes) {
        void* p = (void*)w;
        w += (bytes + 255) & ~(size_t)255;
        return p;
    };
    int*   cnt  = (int*)  carve((size_t)N * 4);
    int*   pos  = (int*)  carve((size_t)N * 4);
    int*   off  = (int*)  carve((size_t)(N + 1) * 4);
    int2*  adj2 = (int2*) carve((size_t)E * 8);
    int*   bsum = (int*)  carve((size_t)NB * 4);
    float* tmp  = (float*)carve((size_t)N * D * 4);
    float* a_s  = (float*)carve((size_t)N * H * 4);
    float* a_d  = (float*)carve((size_t)N * H * 4);
    __hip_bfloat16* xhb = (__hip_bfloat16*)tmp;

    float* h = (float*)d_out;

    hipMemsetAsync(cnt, 0, (size_t)N * 4, stream);
    hipMemsetAsync(pos, 0, (size_t)N * 4, stream);

    int tb = 256;
    k_count<<<(E + tb - 1) / tb, tb, 0, stream>>>(ei, cnt, E);
    k_scan_part<<<NB, 256, 0, stream>>>(cnt, off, bsum, N);
    k_scan_top<<<1, 256, 0, stream>>>(bsum, off, NB, N);
    k_scan_add<<<NB, 256, 0, stream>>>(cnt, off, bsum, N);
    k_fill<<<(E + tb - 1) / tb, tb, 0, stream>>>(ei, off, pos, adj2, E);
    k_gemm<2><<<(N + 63) / 64, 256, 0, stream>>>(
        nullptr, W_node, b_node, h, nullptr, nullptr, nullptr, nullptr, nullptr,
        x, adj2, off, W_edge, b_edge, N);

    int gb = 2048;
    if (gb > (N + 3) / 4) gb = (N + 3) / 4;
    int nwaves = gb * 4;

    for (int i = 0; i < 3; i++) {
        k_gemm<1><<<(N + 63) / 64, 256, 0, stream>>>(
            h, lin_w + (size_t)i * D * D, nullptr, nullptr,
            xhb, a_s, a_d, att_src + i * D, att_dst + i * D,
            nullptr, nullptr, nullptr, nullptr, nullptr, N);
        k_gat4<<<gb, 256, 0, stream>>>(
            xhb, off, adj2, a_s, a_d,
            gat_b + i * D, ln_g + i * D, ln_b + i * D,
            h, N, (i < 2) ? 1 : 0, nwaves);
    }
}

// Round 6
// 351.888 us; speedup vs baseline: 1.1987x; 1.1987x over previous
//
#include <hip/hip_runtime.h>
#include <hip/hip_bf16.h>
#include <math.h>

#define D 128
#define H 4
#define NEG_SLOPE 0.2f
#define LN_EPS 1e-5f

__device__ __forceinline__ float lrelu(float v) {
    return v > 0.f ? v : NEG_SLOPE * v;
}

// ---------- per-destination in-degree histogram (int atomics only) ----------
__global__ void k_count(const int* __restrict__ ei, int* __restrict__ cnt, int E) {
    int e = blockIdx.x * blockDim.x + threadIdx.x;
    if (e >= E) return;
    atomicAdd(&cnt[ei[E + e]], 1);
}

// ---------- hierarchical exclusive scan of cnt[N] -> off[N+1] ----------
__global__ void k_scan_part(const int* __restrict__ cnt, int* __restrict__ off,
                            int* __restrict__ bsum, int N) {
    __shared__ int sm[256];
    int i = blockIdx.x * 256 + threadIdx.x;
    int v = (i < N) ? cnt[i] : 0;
    sm[threadIdx.x] = v;
    __syncthreads();
    #pragma unroll
    for (int o = 1; o < 256; o <<= 1) {
        int t = (threadIdx.x >= (unsigned)o) ? sm[threadIdx.x - o] : 0;
        __syncthreads();
        sm[threadIdx.x] += t;
        __syncthreads();
    }
    if (i < N) off[i] = sm[threadIdx.x];
    if (threadIdx.x == 255) bsum[blockIdx.x] = sm[255];
}

__global__ void k_scan_top(int* __restrict__ bsum, int* __restrict__ off,
                           int NB, int N) {
    __shared__ int sm[256];
    int v = (threadIdx.x < (unsigned)NB) ? bsum[threadIdx.x] : 0;
    sm[threadIdx.x] = v;
    __syncthreads();
    #pragma unroll
    for (int o = 1; o < 256; o <<= 1) {
        int t = (threadIdx.x >= (unsigned)o) ? sm[threadIdx.x - o] : 0;
        __syncthreads();
        sm[threadIdx.x] += t;
        __syncthreads();
    }
    if (threadIdx.x < (unsigned)NB) bsum[threadIdx.x] = sm[threadIdx.x] - v;
    if (threadIdx.x == 255) off[N] = sm[255];
}

__global__ void k_scan_add(const int* __restrict__ cnt, int* __restrict__ off,
                           const int* __restrict__ bsum, int N) {
    int i = blockIdx.x * 256 + threadIdx.x;
    if (i < N) off[i] = off[i] - cnt[i] + bsum[blockIdx.x];
}

// ---------- CSR fill: adj2[slot] = {src, edge_id} (one 8B store) ----------
__global__ void k_fill(const int* __restrict__ ei, const int* __restrict__ off,
                       int* __restrict__ pos, int2* __restrict__ adj2, int E) {
    int e = blockIdx.x * blockDim.x + threadIdx.x;
    if (e >= E) return;
    int dst = ei[E + e];
    int slot = off[dst] + atomicAdd(&pos[dst], 1);
    adj2[slot] = make_int2(ei[e], e);
}

// ---------- GEMM: C[N,128] = A[N,128] @ W[128,128] ----------
// MODE 1: A explicit, bf16 out + fused attention dots.
// MODE 2: A synthesized from scatter-mean (x gathered via CSR, W_edge, b_edge),
//         f32 out + bias.
template <int MODE>
__global__ __launch_bounds__(256) void k_gemm(
        const float* __restrict__ A, const float* __restrict__ W,
        const float* __restrict__ bias, float* __restrict__ C,
        __hip_bfloat16* __restrict__ xhb, float* __restrict__ a_s,
        float* __restrict__ a_d, const float* __restrict__ att_s,
        const float* __restrict__ att_d,
        const float* __restrict__ x, const int2* __restrict__ adj2,
        const int* __restrict__ off,
        const float* __restrict__ W_edge, const float* __restrict__ b_edge,
        int N) {
    __shared__ float As[64][132];
    int tid = threadIdx.x;
    int n0 = blockIdx.x * 64;

    if (MODE == 2) {
        __shared__ float rowf[64][4];
        // gather-sum raw 3-dim edge features: 4 threads per row
        {
            int r = tid >> 2, t4 = tid & 3;
            int n = n0 + r;
            float s0 = 0.f, s1 = 0.f, s2 = 0.f;
            int degv = 0;
            if (n < N) {
                int beg = off[n], end = off[n + 1];
                degv = end - beg;
                for (int p = beg + t4; p < end; p += 4) {
                    const float* xr = x + (size_t)adj2[p].y * 3;
                    s0 += xr[0]; s1 += xr[1]; s2 += xr[2];
                }
            }
            s0 += __shfl_xor(s0, 1); s0 += __shfl_xor(s0, 2);
            s1 += __shfl_xor(s1, 1); s1 += __shfl_xor(s1, 2);
            s2 += __shfl_xor(s2, 1); s2 += __shfl_xor(s2, 2);
            if (t4 == 0)
                *reinterpret_cast<float4*>(rowf[r]) =
                    make_float4(s0, s1, s2, (float)degv);
        }
        __syncthreads();
        int d = tid & 127;
        float we0 = W_edge[d], we1 = W_edge[D + d], we2 = W_edge[2 * D + d];
        float be = b_edge[d];
        for (int r = tid >> 7; r < 64; r += 2) {
            float4 rv = *reinterpret_cast<float4*>(rowf[r]);
            float c = rv.w;
            As[r][d] = (rv.x * we0 + rv.y * we1 + rv.z * we2 + c * be)
                       / fmaxf(c, 1.f);
        }
    } else {
        for (int i = tid; i < 64 * 32; i += 256) {
            int r = i >> 5, q = i & 31;
            int n = n0 + r;
            float4 v = make_float4(0.f, 0.f, 0.f, 0.f);
            if (n < N) v = reinterpret_cast<const float4*>(A)[(size_t)n * 32 + q];
            *reinterpret_cast<float4*>(&As[r][q * 4]) = v;
        }
    }
    __syncthreads();

    int tx = tid & 15, ty = tid >> 4;
    int c0 = tx * 8, r0 = ty * 4;
    float acc[4][8];
    #pragma unroll
    for (int r = 0; r < 4; r++)
        #pragma unroll
        for (int c = 0; c < 8; c++) acc[r][c] = 0.f;

    const float4* Wv = reinterpret_cast<const float4*>(W);
    #pragma unroll 4
    for (int k = 0; k < D; k++) {
        float4 w0 = Wv[k * 32 + tx * 2];
        float4 w1 = Wv[k * 32 + tx * 2 + 1];
        #pragma unroll
        for (int r = 0; r < 4; r++) {
            float a = As[r0 + r][k];
            acc[r][0] += a * w0.x; acc[r][1] += a * w0.y;
            acc[r][2] += a * w0.z; acc[r][3] += a * w0.w;
            acc[r][4] += a * w1.x; acc[r][5] += a * w1.y;
            acc[r][6] += a * w1.z; acc[r][7] += a * w1.w;
        }
    }

    if (MODE == 2) {
        float b[8];
        #pragma unroll
        for (int c = 0; c < 8; c++) b[c] = bias[c0 + c];
        #pragma unroll
        for (int r = 0; r < 4; r++) {
            int n = n0 + r0 + r;
            if (n >= N) continue;
            float4 o0 = make_float4(acc[r][0] + b[0], acc[r][1] + b[1],
                                    acc[r][2] + b[2], acc[r][3] + b[3]);
            float4 o1 = make_float4(acc[r][4] + b[4], acc[r][5] + b[5],
                                    acc[r][6] + b[6], acc[r][7] + b[7]);
            reinterpret_cast<float4*>(C)[(size_t)n * 32 + tx * 2] = o0;
            reinterpret_cast<float4*>(C)[(size_t)n * 32 + tx * 2 + 1] = o1;
        }
    } else {
        float ats[8], atd[8];
        #pragma unroll
        for (int c = 0; c < 8; c++) { ats[c] = att_s[c0 + c]; atd[c] = att_d[c0 + c]; }
        #pragma unroll
        for (int r = 0; r < 4; r++) {
            int n = n0 + r0 + r;
            union { uint4 v; unsigned short s[8]; } pk;
            #pragma unroll
            for (int c = 0; c < 8; c++) {
                __hip_bfloat16 hb = __float2bfloat16(acc[r][c]);
                pk.s[c] = *reinterpret_cast<unsigned short*>(&hb);
            }
            float ps = 0.f, pd = 0.f;
            #pragma unroll
            for (int c = 0; c < 8; c++) { ps += acc[r][c] * ats[c]; pd += acc[r][c] * atd[c]; }
            ps += __shfl_xor(ps, 1); ps += __shfl_xor(ps, 2);
            pd += __shfl_xor(pd, 1); pd += __shfl_xor(pd, 2);
            if (n < N) {
                *reinterpret_cast<uint4*>(xhb + (size_t)n * D + c0) = pk.v;
                if ((tx & 3) == 0) {
                    a_s[n * H + (tx >> 2)] = ps;
                    a_d[n * H + (tx >> 2)] = pd;
                }
            }
        }
    }
}

// ---------- fused GAT aggregate + bias + LN (+ReLU) + residual ----------
// One wave per node, 4 nodes per block. SINGLE PASS: no segment-max
// (lrelu-bounded logits make exp() safe in f32), no LDS, unnormalized
// accumulate + one divide. Lane layout: cl = lane&15 owns channels
// 8*cl..8*cl+7 (head hb = cl>>2); sub = lane>>4 picks 1 of 4 edges in flight.
__global__ __launch_bounds__(256) void k_gat5(
        const __hip_bfloat16* __restrict__ xhb, const int* __restrict__ off,
        const int2* __restrict__ adj2, const float* __restrict__ a_s,
        const float* __restrict__ a_d, const float* __restrict__ bias,
        const float* __restrict__ g, const float* __restrict__ bln,
        float* __restrict__ h, int N, int do_relu) {
    int wid = threadIdx.x >> 6;
    int lane = threadIdx.x & 63;
    int n = blockIdx.x * 4 + wid;
    if (n >= N) return;

    int cl = lane & 15;             // channel group: c0 = 8*cl
    int sub = lane >> 4;            // edge sub-slot (4 edges in flight)
    int hb = cl >> 2;               // head of this lane's channels
    int c0 = cl * 8;

    int beg = off[n], end = off[n + 1];
    int deg = end - beg;
    int items = deg + 1;            // + self loop
    int itp = (items + 3) & ~3;     // padded trip count (uniform across wave)

    float adA = a_d[n * H + hb];
    float den = 0.f;
    float acc[8];
    #pragma unroll
    for (int c = 0; c < 8; c++) acc[c] = 0.f;

    #pragma unroll 4
    for (int pp = sub; pp < itp; pp += 4) {
        int s = (pp < deg) ? adj2[beg + pp].x : n;     // self-loop / pad -> n
        float av = a_s[(size_t)s * H + hb];
        uint4 u = *reinterpret_cast<const uint4*>(xhb + (size_t)s * D + c0);
        float e = lrelu(av + adA);
        float wv = (pp < items) ? __expf(e) : 0.f;     // pad lanes contribute 0
        den += wv;
        float f;
        f = __uint_as_float(u.x << 16);         acc[0] += wv * f;
        f = __uint_as_float(u.x & 0xffff0000u); acc[1] += wv * f;
        f = __uint_as_float(u.y << 16);         acc[2] += wv * f;
        f = __uint_as_float(u.y & 0xffff0000u); acc[3] += wv * f;
        f = __uint_as_float(u.z << 16);         acc[4] += wv * f;
        f = __uint_as_float(u.z & 0xffff0000u); acc[5] += wv * f;
        f = __uint_as_float(u.w << 16);         acc[6] += wv * f;
        f = __uint_as_float(u.w & 0xffff0000u); acc[7] += wv * f;
    }

    // combine the 4 edge sub-slots (lanes cl, cl+16, cl+32, cl+48)
    #pragma unroll
    for (int c = 0; c < 8; c++) {
        acc[c] += __shfl_xor(acc[c], 16);
        acc[c] += __shfl_xor(acc[c], 32);
    }
    den += __shfl_xor(den, 16);
    den += __shfl_xor(den, 32);
    float rden = 1.0f / den;

    float4 b0 = *reinterpret_cast<const float4*>(bias + c0);
    float4 b1 = *reinterpret_cast<const float4*>(bias + c0 + 4);
    float o[8];
    o[0] = acc[0] * rden + b0.x; o[1] = acc[1] * rden + b0.y;
    o[2] = acc[2] * rden + b0.z; o[3] = acc[3] * rden + b0.w;
    o[4] = acc[4] * rden + b1.x; o[5] = acc[5] * rden + b1.y;
    o[6] = acc[6] * rden + b1.z; o[7] = acc[7] * rden + b1.w;

    // LayerNorm (each channel appears 4x across the wave -> divide by 512)
    float s1 = 0.f;
    #pragma unroll
    for (int c = 0; c < 8; c++) s1 += o[c];
    #pragma unroll
    for (int os = 1; os < 64; os <<= 1) s1 += __shfl_xor(s1, os);
    float mu = s1 * (1.0f / 512.0f);
    float s2 = 0.f;
    #pragma unroll
    for (int c = 0; c < 8; c++) { float dv = o[c] - mu; s2 += dv * dv; }
    #pragma unroll
    for (int os = 1; os < 64; os <<= 1) s2 += __shfl_xor(s2, os);
    float inv = rsqrtf(s2 * (1.0f / 512.0f) + LN_EPS);

    if (sub == 0) {
        float4 g0 = *reinterpret_cast<const float4*>(g + c0);
        float4 g1 = *reinterpret_cast<const float4*>(g + c0 + 4);
        float4 l0 = *reinterpret_cast<const float4*>(bln + c0);
        float4 l1 = *reinterpret_cast<const float4*>(bln + c0 + 4);
        float y[8];
        y[0] = (o[0] - mu) * inv * g0.x + l0.x;
        y[1] = (o[1] - mu) * inv * g0.y + l0.y;
        y[2] = (o[2] - mu) * inv * g0.z + l0.z;
        y[3] = (o[3] - mu) * inv * g0.w + l0.w;
        y[4] = (o[4] - mu) * inv * g1.x + l1.x;
        y[5] = (o[5] - mu) * inv * g1.y + l1.y;
        y[6] = (o[6] - mu) * inv * g1.z + l1.z;
        y[7] = (o[7] - mu) * inv * g1.w + l1.w;
        if (do_relu) {
            #pragma unroll
            for (int c = 0; c < 8; c++) y[c] = fmaxf(y[c], 0.f);
        }
        float4 h0 = *reinterpret_cast<float4*>(h + (size_t)n * D + c0);
        float4 h1 = *reinterpret_cast<float4*>(h + (size_t)n * D + c0 + 4);
        h0.x += y[0]; h0.y += y[1]; h0.z += y[2]; h0.w += y[3];
        h1.x += y[4]; h1.y += y[5]; h1.z += y[6]; h1.w += y[7];
        *reinterpret_cast<float4*>(h + (size_t)n * D + c0) = h0;
        *reinterpret_cast<float4*>(h + (size_t)n * D + c0 + 4) = h1;
    }
}

extern "C" void kernel_launch(void* const* d_in, const int* in_sizes, int n_in,
                              void* d_out, int out_size, void* d_ws, size_t ws_size,
                              hipStream_t stream) {
    const float* x       = (const float*)d_in[0];
    const int*   ei      = (const int*)  d_in[1];
    const float* W_edge  = (const float*)d_in[2];
    const float* b_edge  = (const float*)d_in[3];
    const float* W_node  = (const float*)d_in[4];
    const float* b_node  = (const float*)d_in[5];
    const float* lin_w   = (const float*)d_in[6];
    const float* att_src = (const float*)d_in[7];
    const float* att_dst = (const float*)d_in[8];
    const float* gat_b   = (const float*)d_in[9];
    const float* ln_g    = (const float*)d_in[10];
    const float* ln_b    = (const float*)d_in[11];

    int N = out_size / D;
    int E = in_sizes[1] / 2;
    int NB = (N + 255) / 256;

    char* w = (char*)d_ws;
    auto carve = [&](size_t bytes) {
        void* p = (void*)w;
        w += (bytes + 255) & ~(size_t)255;
        return p;
    };
    int*   cnt  = (int*)  carve((size_t)N * 4);
    int*   pos  = (int*)  carve((size_t)N * 4);
    int*   off  = (int*)  carve((size_t)(N + 1) * 4);
    int2*  adj2 = (int2*) carve((size_t)E * 8);
    int*   bsum = (int*)  carve((size_t)NB * 4);
    float* tmp  = (float*)carve((size_t)N * D * 4);
    float* a_s  = (float*)carve((size_t)N * H * 4);
    float* a_d  = (float*)carve((size_t)N * H * 4);
    __hip_bfloat16* xhb = (__hip_bfloat16*)tmp;

    float* h = (float*)d_out;

    hipMemsetAsync(cnt, 0, (size_t)N * 4, stream);
    hipMemsetAsync(pos, 0, (size_t)N * 4, stream);

    int tb = 256;
    k_count<<<(E + tb - 1) / tb, tb, 0, stream>>>(ei, cnt, E);
    k_scan_part<<<NB, 256, 0, stream>>>(cnt, off, bsum, N);
    k_scan_top<<<1, 256, 0, stream>>>(bsum, off, NB, N);
    k_scan_add<<<NB, 256, 0, stream>>>(cnt, off, bsum, N);
    k_fill<<<(E + tb - 1) / tb, tb, 0, stream>>>(ei, off, pos, adj2, E);
    k_gemm<2><<<(N + 63) / 64, 256, 0, stream>>>(
        nullptr, W_node, b_node, h, nullptr, nullptr, nullptr, nullptr, nullptr,
        x, adj2, off, W_edge, b_edge, N);

    for (int i = 0; i < 3; i++) {
        k_gemm<1><<<(N + 63) / 64, 256, 0, stream>>>(
            h, lin_w + (size_t)i * D * D, nullptr, nullptr,
            xhb, a_s, a_d, att_src + i * D, att_dst + i * D,
            nullptr, nullptr, nullptr, nullptr, nullptr, N);
        k_gat5<<<(N + 3) / 4, 256, 0, stream>>>(
            xhb, off, adj2, a_s, a_d,
            gat_b + i * D, ln_g + i * D, ln_b + i * D,
            h, N, (i < 2) ? 1 : 0);
    }
}